// Round 11
// baseline (363.670 us; speedup 1.0000x reference)
//
#include <hip/hip_runtime.h>

typedef unsigned short u16;
typedef unsigned int u32;
typedef __attribute__((ext_vector_type(8))) short bf16x8;
typedef __attribute__((ext_vector_type(4))) float f32x4;

#define B_   2
#define T_   2048
#define C_   2048
#define H_   32
#define KVH_ 8
#define DH_  64
// fused qkv buffer: [B*T][3072]; Q cols 0..2047 (pre-scaled by 0.125*log2e), K 2048..2559, V 2560..3071
#define QKVS 3072
#define KOFF 2048
#define VOFF 2560

__device__ __forceinline__ u16 f2bf(float f) {
  union { float f; unsigned u; } v; v.f = f;
  unsigned r = (v.u + 0x7fffu + ((v.u >> 16) & 1u)) >> 16;
  return (u16)r;
}
__device__ __forceinline__ float bf2f(u16 u) {
  union { unsigned u; float f; } v; v.u = ((unsigned)u) << 16;
  return v.f;
}
__device__ __forceinline__ u32 cvt_pk_bf16(float lo, float hi) {
  u32 r;
  asm("v_cvt_pk_bf16_f32 %0, %1, %2" : "=v"(r) : "v"(lo), "v"(hi));
  return r;
}
__device__ __forceinline__ void async_copy16(void* lds, const void* g) {
  __builtin_amdgcn_global_load_lds((const __attribute__((address_space(1))) void*)g,
                                   (__attribute__((address_space(3))) void*)lds, 16, 0, 0);
}

// ---------------- fp32 -> bf16 elementwise ----------------
__global__ void cvt_bf16_kernel(const float* __restrict__ in, u16* __restrict__ out, int n4) {
  int i = blockIdx.x * 256 + threadIdx.x;
  if (i >= n4) return;
  const float4 v = reinterpret_cast<const float4*>(in)[i];
  union { u16 h[4]; unsigned long long ll; } o;
  o.h[0] = f2bf(v.x); o.h[1] = f2bf(v.y); o.h[2] = f2bf(v.z); o.h[3] = f2bf(v.w);
  reinterpret_cast<unsigned long long*>(out)[i] = o.ll;
}

// ---------------- transpose fp32 [K][N] -> bf16 [N][K] ----------------
__global__ void transpose_w_kernel(const float* __restrict__ W, u16* __restrict__ Wt,
                                   int K_, int N_) {
  __shared__ float tile[32][33];
  int n0 = blockIdx.x * 32, k0 = blockIdx.y * 32;
  int tx = threadIdx.x, ty = threadIdx.y;
#pragma unroll
  for (int i = 0; i < 4; i++)
    tile[ty + i * 8][tx] = W[(long)(k0 + ty + i * 8) * N_ + n0 + tx];
  __syncthreads();
#pragma unroll
  for (int i = 0; i < 4; i++)
    Wt[(long)(n0 + ty + i * 8) * K_ + k0 + tx] = f2bf(tile[tx][ty + i * 8]);
}

// ---------------- RoPE (interleaved pairs), in-place on bf16 ----------------
// Q blocks (blockIdx.x < 4) additionally fold in 0.125*log2e for the exp2-domain softmax.
__global__ void rope_kernel(u16* __restrict__ buf, const float* __restrict__ sT,
                            const float* __restrict__ cT, int rowstride, int ncols) {
  int row = blockIdx.y;
  int c4 = (blockIdx.x * 128 + threadIdx.x) * 4;
  if (c4 >= ncols) return;
  const float S = (blockIdx.x < 4) ? 0.18033688f : 1.0f;  // 0.125 * log2(e) for Q
  int t = row & (T_ - 1);
  int pair = (c4 & (DH_ - 1)) >> 1;
  u16* p = buf + (long)row * rowstride + c4;
  union { u16 h[4]; unsigned long long ll; } v;
  v.ll = *reinterpret_cast<unsigned long long*>(p);
  float x0 = bf2f(v.h[0]), x1 = bf2f(v.h[1]), x2 = bf2f(v.h[2]), x3 = bf2f(v.h[3]);
  float s0 = sT[t * 32 + pair] * S,     c0 = cT[t * 32 + pair] * S;
  float s1 = sT[t * 32 + pair + 1] * S, c1 = cT[t * 32 + pair + 1] * S;
  v.h[0] = f2bf(x0 * c0 - x1 * s0);
  v.h[1] = f2bf(x0 * s0 + x1 * c0);
  v.h[2] = f2bf(x2 * c1 - x3 * s1);
  v.h[3] = f2bf(x2 * s1 + x3 * c1);
  *reinterpret_cast<unsigned long long*>(p) = v.ll;
}

// ---------------- bf16 NT GEMM, BK=64, swizzled LDS (both-sides), XCD swizzle ----------------
// LDS [128 rows][64 k] per matrix; global source chunk pre-swizzled (t&7)^(row&7) so the
// linear global_load_lds dest yields LDS chunk c' holding global chunk c'^(row&7);
// reads XOR with ((lr&7)<<4). Each 8-lane group covers all 8 chunks -> conflict-free.
template <int OUT_F32>
__global__ __launch_bounds__(256, 3) void gemm_nt(const u16* __restrict__ A,
                                                  const u16* __restrict__ Bt,
                                                  void* __restrict__ Cout,
                                                  int M_, int N_, int K_) {
  __shared__ alignas(16) u16 As[128 * 64];
  __shared__ alignas(16) u16 Bs[128 * 64];
  const int t = threadIdx.x;
  const int w = t >> 6, l = t & 63;
  // XCD-aware bijective swizzle (requires nwg % 8 == 0; all our launches satisfy this)
  const int gx = gridDim.x;
  const int nwg = gx * gridDim.y;
  const int flat = blockIdx.y * gx + blockIdx.x;
  const int f2 = (flat & 7) * (nwg >> 3) + (flat >> 3);
  const int m0 = (f2 / gx) * 128, n0 = (f2 % gx) * 128;
  const int wr = (w >> 1) * 64, wc = (w & 1) * 64;
  const int lr = l & 15, lg = l >> 4;
  const int rswz = (lr & 7) << 4;

  f32x4 acc[4][4];
#pragma unroll
  for (int i = 0; i < 4; i++)
#pragma unroll
    for (int j = 0; j < 4; j++) {
      f32x4 z = {0.f, 0.f, 0.f, 0.f};
      acc[i][j] = z;
    }

  const int arow = t >> 3;                       // 0..31 (row within 32-row round)
  const int achk = (t & 7) ^ (arow & 7);         // pre-swizzled source chunk
  const u16* Ag = A + (long)(m0 + arow) * K_ + achk * 8;
  const u16* Bg = Bt + (long)(n0 + arow) * K_ + achk * 8;
  char* AsB = (char*)As;
  char* BsB = (char*)Bs;
  const int wbase = (w << 10);

  for (int kt = 0; kt < K_; kt += 64) {
#pragma unroll
    for (int r = 0; r < 4; r++) {
      async_copy16(AsB + r * 4096 + wbase, Ag + kt + (long)(32 * r) * K_);
      async_copy16(BsB + r * 4096 + wbase, Bg + kt + (long)(32 * r) * K_);
    }
    __syncthreads();
#pragma unroll
    for (int kk = 0; kk < 2; kk++) {
      bf16x8 a[4], b[4];
#pragma unroll
      for (int i = 0; i < 4; i++)
        a[i] = *(const bf16x8*)(AsB + (wr + i * 16 + lr) * 128 + ((kk * 64 + lg * 16) ^ rswz));
#pragma unroll
      for (int i = 0; i < 4; i++)
        b[i] = *(const bf16x8*)(BsB + (wc + i * 16 + lr) * 128 + ((kk * 64 + lg * 16) ^ rswz));
#pragma unroll
      for (int i = 0; i < 4; i++)
#pragma unroll
        for (int j = 0; j < 4; j++)
          acc[i][j] = __builtin_amdgcn_mfma_f32_16x16x32_bf16(a[i], b[j], acc[i][j], 0, 0, 0);
    }
    __syncthreads();
  }

#pragma unroll
  for (int i = 0; i < 4; i++)
#pragma unroll
    for (int j = 0; j < 4; j++)
#pragma unroll
      for (int r = 0; r < 4; r++) {
        long row = m0 + wr + i * 16 + lg * 4 + r;
        long col = n0 + wc + j * 16 + lr;
        float v = acc[i][j][r];
        if (OUT_F32)
          ((float*)Cout)[row * N_ + col] = v;
        else
          ((u16*)Cout)[row * N_ + col] = f2bf(v);
      }
}

// ---------------- flash attention (GQA, causal + SWA), swapped-QK^T, KVBLK=128 ----------------
// qkv: [B*T][3072] bf16; o: [B*T][2048] bf16. Q pre-scaled by 0.125*log2e -> exp2-domain softmax.
// Block bx processes q-tiles {bx, 31-bx}; KV tiles are 128 wide -> 17 tile-iters per block (const).
// Klds [128 kv][64 d] (16KB), VTlds [64 d][128 kv] (16KB), P per-wave [16 q][64 kv] (8KB) = 40KB.
__global__ __launch_bounds__(256, 3) void attn_fwd(const u16* __restrict__ qkv,
                                                   u16* __restrict__ o,
                                                   const int* __restrict__ swa_ptr) {
  __shared__ alignas(16) u16 Klds[128 * 64];
  __shared__ alignas(16) u16 VTlds[64 * 128];
  __shared__ alignas(16) u16 Plds[4][16 * 64];
  const int t = threadIdx.x, w = t >> 6, l = t & 63;
  // XCD swizzle over flat grid (16,32,2) = 1024 blocks; chunk = 128 per XCD
  const int flat = blockIdx.x + (blockIdx.y << 4) + (blockIdx.z << 9);
  const int f2 = (flat & 7) * 128 + (flat >> 3);
  const int bx = f2 & 15, h = (f2 >> 4) & 31, b = f2 >> 9;
  const int kvh = h >> 2;
  const int swa = *swa_ptr;
  const int lr = l & 15, lg = l >> 4;
  const int swz = (lr & 7) << 4;
  const int sbase = (l & 48) | (lg << 2);  // shfl src base for per-row fac/inv
  char* myP = (char*)Plds + w * 2048;

  // staging thread roles
  const int krow = t >> 3, kch = t & 7;              // K: rows krow + 32r, 8 bf16 cols
  const int kvp = (t & 63) * 2, dch = (t >> 6) * 8;  // V: kv pair (0..126), d-chunk (0..24; +32 rnd 2)

  for (int pass = 0; pass < 2; pass++) {
    const int qtile = pass ? (31 - bx) : bx;
    const int q0 = qtile * 64;

    // Q as B-operand: lane holds Q[q=lr][d = kk*32 + lg*8 + j]
    bf16x8 qa[2];
    const long qrow = (long)(b * T_ + q0 + w * 16 + lr);
#pragma unroll
    for (int kk = 0; kk < 2; kk++)
      qa[kk] = *(const bf16x8*)(qkv + qrow * QKVS + h * 64 + kk * 32 + lg * 8);

    f32x4 ofrag[4];
#pragma unroll
    for (int nf = 0; nf < 4; nf++) {
      f32x4 z = {0.f, 0.f, 0.f, 0.f};
      ofrag[nf] = z;
    }
    float mrun = -1e30f, srun = 0.f;

    const int lastt = qtile >> 1;
    const int lo = q0 - swa;
    const int startt = lo > 0 ? (lo >> 7) : 0;

    // ---- prologue: load first 128-kv tile into regs ----
    bf16x8 K0, K1, K2, K3, Va0, Va1, Vb0, Vb1;
    {
      const u16* kb = qkv + (long)(b * T_ + startt * 128) * QKVS + KOFF + kvh * 64;
      K0 = *(const bf16x8*)(kb + (long)krow * QKVS + kch * 8);
      K1 = *(const bf16x8*)(kb + (long)(krow + 32) * QKVS + kch * 8);
      K2 = *(const bf16x8*)(kb + (long)(krow + 64) * QKVS + kch * 8);
      K3 = *(const bf16x8*)(kb + (long)(krow + 96) * QKVS + kch * 8);
      const u16* vb = qkv + (long)(b * T_ + startt * 128) * QKVS + VOFF + kvh * 64;
      Va0 = *(const bf16x8*)(vb + (long)kvp * QKVS + dch);
      Va1 = *(const bf16x8*)(vb + (long)(kvp + 1) * QKVS + dch);
      Vb0 = *(const bf16x8*)(vb + (long)kvp * QKVS + dch + 32);
      Vb1 = *(const bf16x8*)(vb + (long)(kvp + 1) * QKVS + dch + 32);
    }

    for (int tt = startt; tt <= lastt; tt++) {
      const int kv0 = tt * 128;
      __syncthreads();  // prior tile's (or prior pass's) LDS reads complete
      // ---- stage K [128][64] from regs, swizzled ----
      const int kkey = (krow & 7) << 4;
      *(bf16x8*)((char*)Klds + ((krow * 128 + kch * 16) ^ kkey)) = K0;
      *(bf16x8*)((char*)Klds + (((krow + 32) * 128 + kch * 16) ^ kkey)) = K1;
      *(bf16x8*)((char*)Klds + (((krow + 64) * 128 + kch * 16) ^ kkey)) = K2;
      *(bf16x8*)((char*)Klds + (((krow + 96) * 128 + kch * 16) ^ kkey)) = K3;
      // ---- stage V^T [64][128] from regs (paired-kv u32 writes) ----
#pragma unroll
      for (int i = 0; i < 8; i++) {
        int d = dch + i;
        int off = (d * 256 + kvp * 2) ^ ((i & 7) << 4);
        *(u32*)((char*)VTlds + off) = ((u32)(u16)Va0[i]) | (((u32)(u16)Va1[i]) << 16);
        int d2 = d + 32;
        int off2 = (d2 * 256 + kvp * 2) ^ ((i & 7) << 4);
        *(u32*)((char*)VTlds + off2) = ((u32)(u16)Vb0[i]) | (((u32)(u16)Vb1[i]) << 16);
      }
      __syncthreads();
      // ---- prefetch next tile into regs (overlaps with compute below) ----
      if (tt < lastt) {
        const u16* kb = qkv + (long)(b * T_ + kv0 + 128) * QKVS + KOFF + kvh * 64;
        K0 = *(const bf16x8*)(kb + (long)krow * QKVS + kch * 8);
        K1 = *(const bf16x8*)(kb + (long)(krow + 32) * QKVS + kch * 8);
        K2 = *(const bf16x8*)(kb + (long)(krow + 64) * QKVS + kch * 8);
        K3 = *(const bf16x8*)(kb + (long)(krow + 96) * QKVS + kch * 8);
        const u16* vb = qkv + (long)(b * T_ + kv0 + 128) * QKVS + VOFF + kvh * 64;
        Va0 = *(const bf16x8*)(vb + (long)kvp * QKVS + dch);
        Va1 = *(const bf16x8*)(vb + (long)(kvp + 1) * QKVS + dch);
        Vb0 = *(const bf16x8*)(vb + (long)kvp * QKVS + dch + 32);
        Vb1 = *(const bf16x8*)(vb + (long)(kvp + 1) * QKVS + dch + 32);
      }

      // ---- S^T = K Q^T : 8 kv-frags x 16 q (log2 domain) ----
      f32x4 s[8];
#pragma unroll
      for (int nf = 0; nf < 8; nf++) {
        f32x4 acc = {0.f, 0.f, 0.f, 0.f};
#pragma unroll
        for (int kk = 0; kk < 2; kk++) {
          int koff = ((nf * 16 + lr) * 128 + (kk * 32 + lg * 8) * 2) ^ swz;
          bf16x8 kb = *(const bf16x8*)((char*)Klds + koff);
          acc = __builtin_amdgcn_mfma_f32_16x16x32_bf16(kb, qa[kk], acc, 0, 0, 0);
        }
        s[nf] = acc;
      }

      // ---- mask only when tile intersects causal/window boundary (wave-uniform) ----
      const int i_abs = q0 + w * 16 + lr;
      const int wmin = q0 + w * 16;
      float pm = -3e38f;
      if ((kv0 + 127 > wmin) || (wmin + 15 - kv0 > swa)) {
#pragma unroll
        for (int nf = 0; nf < 8; nf++)
#pragma unroll
          for (int r = 0; r < 4; r++) {
            int j = kv0 + nf * 16 + lg * 4 + r;
            bool ok = (j <= i_abs) && (i_abs - j <= swa);
            float sv = ok ? s[nf][r] : -3e38f;
            s[nf][r] = sv;
            pm = fmaxf(pm, sv);
          }
      } else {
#pragma unroll
        for (int nf = 0; nf < 8; nf++)
#pragma unroll
          for (int r = 0; r < 4; r++) pm = fmaxf(pm, s[nf][r]);
      }
      pm = fmaxf(pm, __shfl_xor(pm, 16));
      pm = fmaxf(pm, __shfl_xor(pm, 32));

      float mnew = fmaxf(mrun, pm);
      float fac = exp2f(mrun - mnew);
      mrun = mnew;
      float rs = 0.f;
#pragma unroll
      for (int nf = 0; nf < 8; nf++)
#pragma unroll
        for (int r = 0; r < 4; r++) {
          float p = exp2f(s[nf][r] - mrun);
          s[nf][r] = p;
          rs += p;
        }
      rs += __shfl_xor(rs, 16);
      rs += __shfl_xor(rs, 32);
      srun = srun * fac + rs;

      // ---- PV in two 64-kv halves through the per-wave P buffer ----
#pragma unroll
      for (int hh = 0; hh < 2; hh++) {
#pragma unroll
        for (int n2 = 0; n2 < 4; n2++) {
          int nf = hh * 4 + n2;
          u32 lo32 = cvt_pk_bf16(s[nf][0], s[nf][1]);
          u32 hi32 = cvt_pk_bf16(s[nf][2], s[nf][3]);
          unsigned long long pk = ((unsigned long long)hi32 << 32) | lo32;
          int off = (lr * 128 + n2 * 32 + lg * 8) ^ swz;
          *(unsigned long long*)(myP + off) = pk;
        }
        if (hh == 0) {
          // rescale O while the P writes drain (once per tile)
          float facr[4];
#pragma unroll
          for (int r = 0; r < 4; r++) facr[r] = __shfl(fac, sbase + r);
#pragma unroll
          for (int nf = 0; nf < 4; nf++)
#pragma unroll
            for (int r = 0; r < 4; r++) ofrag[nf][r] *= facr[r];
        }
        asm volatile("s_waitcnt lgkmcnt(0)" ::: "memory");
        bf16x8 pa[2];
#pragma unroll
        for (int kk = 0; kk < 2; kk++) {
          int poff = (lr * 128 + kk * 64 + lg * 16) ^ swz;
          pa[kk] = *(const bf16x8*)(myP + poff);
        }
#pragma unroll
        for (int nf = 0; nf < 4; nf++)
#pragma unroll
          for (int kk = 0; kk < 2; kk++) {
            int voff = ((nf * 16 + lr) * 256 + (hh * 64 + kk * 32 + lg * 8) * 2) ^ swz;
            bf16x8 vb = *(const bf16x8*)((char*)VTlds + voff);
            ofrag[nf] = __builtin_amdgcn_mfma_f32_16x16x32_bf16(pa[kk], vb, ofrag[nf], 0, 0, 0);
          }
      }
    }

    // ---- epilogue: O rows q = lg*4+r, cols d = nf*16+lr ----
    float inv = 1.0f / srun;
    float invr[4];
#pragma unroll
    for (int r = 0; r < 4; r++) invr[r] = __shfl(inv, sbase + r);
    const long orow = (long)(b * T_ + q0 + w * 16);
#pragma unroll
    for (int nf = 0; nf < 4; nf++)
#pragma unroll
      for (int r = 0; r < 4; r++)
        o[(orow + lg * 4 + r) * 2048 + h * 64 + nf * 16 + lr] = f2bf(ofrag[nf][r] * invr[r]);
  }
}

// ---------------- launch ----------------
// Workspace layout (52 MB, temporally-disjoint aliases):
//   [0,   16M) xb (x bf16)   -> reused as ab (attn out) after fused GEMM
//   [16M, 28M) wqkvT [3072][2048] (Wq^T | Wk^T | Wv^T) -> woT [2048][2048] reuses [16M,24M)
//   [28M, 52M) qkvb [4096][3072]
extern "C" void kernel_launch(void* const* d_in, const int* in_sizes, int n_in,
                              void* d_out, int out_size, void* d_ws, size_t ws_size,
                              hipStream_t stream) {
  const float* x    = (const float*)d_in[0];
  const float* Wq   = (const float*)d_in[1];
  const float* Wk   = (const float*)d_in[2];
  const float* Wv   = (const float*)d_in[3];
  const float* Wout = (const float*)d_in[4];
  const float* rsin = (const float*)d_in[5];
  const float* rcos = (const float*)d_in[6];
  const int*   swa  = (const int*)d_in[7];
  float* out = (float*)d_out;

  char* ws = (char*)d_ws;
  u16* xb    = (u16*)(ws);                      // [4096][2048]
  u16* ab    = xb;                              // alias: written after xb dead
  u16* wqkvT = (u16*)(ws + 16777216);           // [3072][2048]
  u16* woT   = wqkvT;                           // alias: written after wqkvT dead
  u16* qkvb  = (u16*)(ws + 29360128);           // [4096][3072]

  cvt_bf16_kernel<<<dim3(8192), dim3(256), 0, stream>>>(x, xb, 2097152);
  transpose_w_kernel<<<dim3(64, 64), dim3(32, 8), 0, stream>>>(Wq, wqkvT, 2048, 2048);
  transpose_w_kernel<<<dim3(16, 64), dim3(32, 8), 0, stream>>>(Wk, wqkvT + (long)2048 * 2048, 2048, 512);
  transpose_w_kernel<<<dim3(16, 64), dim3(32, 8), 0, stream>>>(Wv, wqkvT + (long)2560 * 2048, 2048, 512);

  // fused QKV projection: [4096][2048] x [3072][2048]^T -> [4096][3072]
  gemm_nt<0><<<dim3(24, 32), dim3(256), 0, stream>>>(xb, wqkvT, qkvb, 4096, 3072, 2048);

  // Wout^T into first 8MB of wqkvT's space (dead after fused GEMM)
  transpose_w_kernel<<<dim3(64, 64), dim3(32, 8), 0, stream>>>(Wout, woT, 2048, 2048);

  // RoPE over Q (cols 0..2047, folds softmax scale) + K (cols 2048..2559); V untouched
  rope_kernel<<<dim3(5, 4096), dim3(128), 0, stream>>>(qkvb, rsin, rcos, QKVS, 2560);

  // attn writes ab (= xb space); paired q-tiles, KVBLK=128: grid.x = 16
  attn_fwd<<<dim3(16, 32, 2), dim3(256), 0, stream>>>(qkvb, ab, swa);

  gemm_nt<1><<<dim3(16, 32), dim3(256), 0, stream>>>(ab, woT, out, 4096, 2048, 2048);
}

// Round 12
// 313.937 us; speedup vs baseline: 1.1584x; 1.1584x over previous
//
#include <hip/hip_runtime.h>

typedef unsigned short u16;
typedef unsigned int u32;
typedef __attribute__((ext_vector_type(8))) short bf16x8;
typedef __attribute__((ext_vector_type(4))) float f32x4;

#define B_   2
#define T_   2048
#define C_   2048
#define H_   32
#define KVH_ 8
#define DH_  64
// fused qkv buffer: [B*T][3072]; Q cols 0..2047 (pre-scaled by 0.125*log2e), K 2048..2559, V 2560..3071
#define QKVS 3072
#define KOFF 2048
#define VOFF 2560

__device__ __forceinline__ u16 f2bf(float f) {
  union { float f; unsigned u; } v; v.f = f;
  unsigned r = (v.u + 0x7fffu + ((v.u >> 16) & 1u)) >> 16;
  return (u16)r;
}
__device__ __forceinline__ float bf2f(u16 u) {
  union { unsigned u; float f; } v; v.u = ((unsigned)u) << 16;
  return v.f;
}
__device__ __forceinline__ u32 cvt_pk_bf16(float lo, float hi) {
  u32 r;
  asm("v_cvt_pk_bf16_f32 %0, %1, %2" : "=v"(r) : "v"(lo), "v"(hi));
  return r;
}
__device__ __forceinline__ void async_copy16(void* lds, const void* g) {
  __builtin_amdgcn_global_load_lds((const __attribute__((address_space(1))) void*)g,
                                   (__attribute__((address_space(3))) void*)lds, 16, 0, 0);
}

// ---------------- fp32 -> bf16 elementwise ----------------
__global__ void cvt_bf16_kernel(const float* __restrict__ in, u16* __restrict__ out, int n4) {
  int i = blockIdx.x * 256 + threadIdx.x;
  if (i >= n4) return;
  const float4 v = reinterpret_cast<const float4*>(in)[i];
  union { u16 h[4]; unsigned long long ll; } o;
  o.h[0] = f2bf(v.x); o.h[1] = f2bf(v.y); o.h[2] = f2bf(v.z); o.h[3] = f2bf(v.w);
  reinterpret_cast<unsigned long long*>(out)[i] = o.ll;
}

// ---------------- transpose fp32 [K][N] -> bf16 [N][K] ----------------
__global__ void transpose_w_kernel(const float* __restrict__ W, u16* __restrict__ Wt,
                                   int K_, int N_) {
  __shared__ float tile[32][33];
  int n0 = blockIdx.x * 32, k0 = blockIdx.y * 32;
  int tx = threadIdx.x, ty = threadIdx.y;
#pragma unroll
  for (int i = 0; i < 4; i++)
    tile[ty + i * 8][tx] = W[(long)(k0 + ty + i * 8) * N_ + n0 + tx];
  __syncthreads();
#pragma unroll
  for (int i = 0; i < 4; i++)
    Wt[(long)(n0 + ty + i * 8) * K_ + k0 + tx] = f2bf(tile[tx][ty + i * 8]);
}

// ---------------- RoPE (interleaved pairs), in-place on bf16 ----------------
// Q blocks (blockIdx.x < 4) additionally fold in 0.125*log2e for the exp2-domain softmax.
__global__ void rope_kernel(u16* __restrict__ buf, const float* __restrict__ sT,
                            const float* __restrict__ cT, int rowstride, int ncols) {
  int row = blockIdx.y;
  int c4 = (blockIdx.x * 128 + threadIdx.x) * 4;
  if (c4 >= ncols) return;
  const float S = (blockIdx.x < 4) ? 0.18033688f : 1.0f;  // 0.125 * log2(e) for Q
  int t = row & (T_ - 1);
  int pair = (c4 & (DH_ - 1)) >> 1;
  u16* p = buf + (long)row * rowstride + c4;
  union { u16 h[4]; unsigned long long ll; } v;
  v.ll = *reinterpret_cast<unsigned long long*>(p);
  float x0 = bf2f(v.h[0]), x1 = bf2f(v.h[1]), x2 = bf2f(v.h[2]), x3 = bf2f(v.h[3]);
  float s0 = sT[t * 32 + pair] * S,     c0 = cT[t * 32 + pair] * S;
  float s1 = sT[t * 32 + pair + 1] * S, c1 = cT[t * 32 + pair + 1] * S;
  v.h[0] = f2bf(x0 * c0 - x1 * s0);
  v.h[1] = f2bf(x0 * s0 + x1 * c0);
  v.h[2] = f2bf(x2 * c1 - x3 * s1);
  v.h[3] = f2bf(x2 * s1 + x3 * c1);
  *reinterpret_cast<unsigned long long*>(p) = v.ll;
}

// ---------------- bf16 NT GEMM, BK=64, swizzled LDS (both-sides), XCD swizzle ----------------
// LDS [128 rows][64 k] per matrix; global source chunk pre-swizzled (t&7)^(row&7) so the
// linear global_load_lds dest yields LDS chunk c' holding global chunk c'^(row&7);
// reads XOR with ((lr&7)<<4). Each 8-lane group covers all 8 chunks -> conflict-free.
template <int OUT_F32>
__global__ __launch_bounds__(256, 3) void gemm_nt(const u16* __restrict__ A,
                                                  const u16* __restrict__ Bt,
                                                  void* __restrict__ Cout,
                                                  int M_, int N_, int K_) {
  __shared__ alignas(16) u16 As[128 * 64];
  __shared__ alignas(16) u16 Bs[128 * 64];
  const int t = threadIdx.x;
  const int w = t >> 6, l = t & 63;
  // XCD-aware bijective swizzle (requires nwg % 8 == 0; all our launches satisfy this)
  const int gx = gridDim.x;
  const int nwg = gx * gridDim.y;
  const int flat = blockIdx.y * gx + blockIdx.x;
  const int f2 = (flat & 7) * (nwg >> 3) + (flat >> 3);
  const int m0 = (f2 / gx) * 128, n0 = (f2 % gx) * 128;
  const int wr = (w >> 1) * 64, wc = (w & 1) * 64;
  const int lr = l & 15, lg = l >> 4;
  const int rswz = (lr & 7) << 4;

  f32x4 acc[4][4];
#pragma unroll
  for (int i = 0; i < 4; i++)
#pragma unroll
    for (int j = 0; j < 4; j++) {
      f32x4 z = {0.f, 0.f, 0.f, 0.f};
      acc[i][j] = z;
    }

  const int arow = t >> 3;                       // 0..31 (row within 32-row round)
  const int achk = (t & 7) ^ (arow & 7);         // pre-swizzled source chunk
  const u16* Ag = A + (long)(m0 + arow) * K_ + achk * 8;
  const u16* Bg = Bt + (long)(n0 + arow) * K_ + achk * 8;
  char* AsB = (char*)As;
  char* BsB = (char*)Bs;
  const int wbase = (w << 10);

  for (int kt = 0; kt < K_; kt += 64) {
#pragma unroll
    for (int r = 0; r < 4; r++) {
      async_copy16(AsB + r * 4096 + wbase, Ag + kt + (long)(32 * r) * K_);
      async_copy16(BsB + r * 4096 + wbase, Bg + kt + (long)(32 * r) * K_);
    }
    __syncthreads();
#pragma unroll
    for (int kk = 0; kk < 2; kk++) {
      bf16x8 a[4], b[4];
#pragma unroll
      for (int i = 0; i < 4; i++)
        a[i] = *(const bf16x8*)(AsB + (wr + i * 16 + lr) * 128 + ((kk * 64 + lg * 16) ^ rswz));
#pragma unroll
      for (int i = 0; i < 4; i++)
        b[i] = *(const bf16x8*)(BsB + (wc + i * 16 + lr) * 128 + ((kk * 64 + lg * 16) ^ rswz));
#pragma unroll
      for (int i = 0; i < 4; i++)
#pragma unroll
        for (int j = 0; j < 4; j++)
          acc[i][j] = __builtin_amdgcn_mfma_f32_16x16x32_bf16(a[i], b[j], acc[i][j], 0, 0, 0);
    }
    __syncthreads();
  }

#pragma unroll
  for (int i = 0; i < 4; i++)
#pragma unroll
    for (int j = 0; j < 4; j++)
#pragma unroll
      for (int r = 0; r < 4; r++) {
        long row = m0 + wr + i * 16 + lg * 4 + r;
        long col = n0 + wc + j * 16 + lr;
        float v = acc[i][j][r];
        if (OUT_F32)
          ((float*)Cout)[row * N_ + col] = v;
        else
          ((u16*)Cout)[row * N_ + col] = f2bf(v);
      }
}

// ---------------- flash attention (GQA, causal + SWA), swapped-QK^T, paired q-tiles ----------------
// [REVERTED to the measured-99us R9 structure: KVBLK=64, 24KB LDS]
// qkv: [B*T][3072] bf16; o: [B*T][2048] bf16. Q pre-scaled by 0.125*log2e -> exp2-domain softmax.
// Block bx processes q-tiles {bx, 31-bx} -> constant 33 kv-tile computes per block.
// Interior tiles skip masking entirely (wave-uniform test).
__global__ __launch_bounds__(256, 3) void attn_fwd(const u16* __restrict__ qkv,
                                                   u16* __restrict__ o,
                                                   const int* __restrict__ swa_ptr) {
  __shared__ alignas(16) u16 Klds[64 * 64];
  __shared__ alignas(16) u16 VTlds[64 * 64];
  __shared__ alignas(16) u16 Plds[4][16 * 64];
  const int t = threadIdx.x, w = t >> 6, l = t & 63;
  // XCD swizzle over flat grid (16,32,2) = 1024 blocks; chunk = 128 per XCD
  const int flat = blockIdx.x + (blockIdx.y << 4) + (blockIdx.z << 9);
  const int f2 = (flat & 7) * 128 + (flat >> 3);
  const int bx = f2 & 15, h = (f2 >> 4) & 31, b = f2 >> 9;
  const int kvh = h >> 2;
  const int swa = *swa_ptr;
  const int lr = l & 15, lg = l >> 4;
  const int swz = (lr & 7) << 4;
  const int sbase = (l & 48) | (lg << 2);  // shfl src base for per-row fac/inv
  char* myP = (char*)Plds + w * 2048;

  // staging thread roles
  const int krow = t >> 3, kch = t & 7;              // K: rows krow, krow+32; 8 bf16 cols
  const int kvp = (t & 31) * 2, dch = (t >> 5) * 8;  // V: kv pair, d-chunk

  for (int pass = 0; pass < 2; pass++) {
    const int qtile = pass ? (31 - bx) : bx;
    const int q0 = qtile * 64;

    // Q as B-operand: lane holds Q[q=lr][d = kk*32 + lg*8 + j]
    bf16x8 qa[2];
    const long qrow = (long)(b * T_ + q0 + w * 16 + lr);
#pragma unroll
    for (int kk = 0; kk < 2; kk++)
      qa[kk] = *(const bf16x8*)(qkv + qrow * QKVS + h * 64 + kk * 32 + lg * 8);

    f32x4 ofrag[4];
#pragma unroll
    for (int nf = 0; nf < 4; nf++) {
      f32x4 z = {0.f, 0.f, 0.f, 0.f};
      ofrag[nf] = z;
    }
    float mrun = -1e30f, srun = 0.f;

    const int lo = q0 - swa - 63;
    const int startt = lo > 0 ? ((lo + 63) >> 6) : 0;

    // ---- prologue: load first tile into regs ----
    bf16x8 K0, K1, V0, V1;
    {
      const u16* kbase = qkv + (long)(b * T_ + startt * 64) * QKVS + KOFF + kvh * 64;
      K0 = *(const bf16x8*)(kbase + (long)krow * QKVS + kch * 8);
      K1 = *(const bf16x8*)(kbase + (long)(krow + 32) * QKVS + kch * 8);
      const u16* vbase = qkv + (long)(b * T_ + startt * 64) * QKVS + VOFF + kvh * 64 + dch;
      V0 = *(const bf16x8*)(vbase + (long)kvp * QKVS);
      V1 = *(const bf16x8*)(vbase + (long)(kvp + 1) * QKVS);
    }

    for (int tt = startt; tt <= qtile; tt++) {
      const int kv0 = tt * 64;
      __syncthreads();  // prior tile's (or prior pass's) LDS reads complete
      // ---- stage K from regs ----
      *(bf16x8*)((char*)Klds + ((krow * 128 + kch * 16) ^ ((krow & 7) << 4))) = K0;
      *(bf16x8*)((char*)Klds + (((krow + 32) * 128 + kch * 16) ^ ((krow & 7) << 4))) = K1;
      // ---- stage V^T from regs (paired-kv u32 writes) ----
#pragma unroll
      for (int i = 0; i < 8; i++) {
        int d = dch + i;
        int off = (d * 128 + kvp * 2) ^ ((d & 7) << 4);
        u32 pack = ((u32)(u16)V0[i]) | (((u32)(u16)V1[i]) << 16);
        *(u32*)((char*)VTlds + off) = pack;
      }
      __syncthreads();
      // ---- prefetch next tile into regs (overlaps with compute below) ----
      if (tt < qtile) {
        const u16* kbase = qkv + (long)(b * T_ + kv0 + 64) * QKVS + KOFF + kvh * 64;
        K0 = *(const bf16x8*)(kbase + (long)krow * QKVS + kch * 8);
        K1 = *(const bf16x8*)(kbase + (long)(krow + 32) * QKVS + kch * 8);
        const u16* vbase = qkv + (long)(b * T_ + kv0 + 64) * QKVS + VOFF + kvh * 64 + dch;
        V0 = *(const bf16x8*)(vbase + (long)kvp * QKVS);
        V1 = *(const bf16x8*)(vbase + (long)(kvp + 1) * QKVS);
      }

      // ---- S^T = K Q^T : rows kv, cols q (values already in log2 domain) ----
      f32x4 s[4];
#pragma unroll
      for (int nf = 0; nf < 4; nf++) {
        f32x4 acc = {0.f, 0.f, 0.f, 0.f};
#pragma unroll
        for (int kk = 0; kk < 2; kk++) {
          int koff = ((nf * 16 + lr) * 128 + (kk * 32 + lg * 8) * 2) ^ swz;
          bf16x8 kb = *(const bf16x8*)((char*)Klds + koff);
          acc = __builtin_amdgcn_mfma_f32_16x16x32_bf16(kb, qa[kk], acc, 0, 0, 0);
        }
        s[nf] = acc;
      }

      // ---- mask only when the tile intersects the causal/window boundary (wave-uniform) ----
      const int i_abs = q0 + w * 16 + lr;
      const int wmin = q0 + w * 16;
      float pm = -3e38f;
      if ((kv0 + 63 > wmin) || (wmin + 15 - kv0 > swa)) {
#pragma unroll
        for (int nf = 0; nf < 4; nf++)
#pragma unroll
          for (int r = 0; r < 4; r++) {
            int j = kv0 + nf * 16 + lg * 4 + r;
            bool ok = (j <= i_abs) && (i_abs - j <= swa);
            float sv = ok ? s[nf][r] : -3e38f;
            s[nf][r] = sv;
            pm = fmaxf(pm, sv);
          }
      } else {
#pragma unroll
        for (int nf = 0; nf < 4; nf++)
#pragma unroll
          for (int r = 0; r < 4; r++) pm = fmaxf(pm, s[nf][r]);
      }
      pm = fmaxf(pm, __shfl_xor(pm, 16));
      pm = fmaxf(pm, __shfl_xor(pm, 32));

      float mnew = fmaxf(mrun, pm);
      float fac = exp2f(mrun - mnew);
      mrun = mnew;
      float rs = 0.f;
#pragma unroll
      for (int nf = 0; nf < 4; nf++)
#pragma unroll
        for (int r = 0; r < 4; r++) {
          float p = exp2f(s[nf][r] - mrun);
          s[nf][r] = p;
          rs += p;
        }
      rs += __shfl_xor(rs, 16);
      rs += __shfl_xor(rs, 32);
      srun = srun * fac + rs;

      // ---- P -> LDS rows [q=lr][kv], cvt_pk + packed b64 writes ----
#pragma unroll
      for (int nf = 0; nf < 4; nf++) {
        u32 lo32 = cvt_pk_bf16(s[nf][0], s[nf][1]);
        u32 hi32 = cvt_pk_bf16(s[nf][2], s[nf][3]);
        unsigned long long pk = ((unsigned long long)hi32 << 32) | lo32;
        int off = (lr * 128 + nf * 32 + lg * 8) ^ swz;
        *(unsigned long long*)(myP + off) = pk;
      }

      // ---- rescale O (fac per output row q = lg*4+r via shfl) ----
      float facr[4];
#pragma unroll
      for (int r = 0; r < 4; r++) facr[r] = __shfl(fac, sbase + r);
#pragma unroll
      for (int nf = 0; nf < 4; nf++)
#pragma unroll
        for (int r = 0; r < 4; r++) ofrag[nf][r] *= facr[r];

      // ---- fence cross-lane ds_write -> ds_read (same wave) ----
      asm volatile("s_waitcnt lgkmcnt(0)" ::: "memory");
      bf16x8 pa[2];
#pragma unroll
      for (int kk = 0; kk < 2; kk++) {
        int poff = (lr * 128 + kk * 64 + lg * 16) ^ swz;
        pa[kk] = *(const bf16x8*)(myP + poff);
      }
      // ---- O += P V ----
#pragma unroll
      for (int nf = 0; nf < 4; nf++)
#pragma unroll
        for (int kk = 0; kk < 2; kk++) {
          int voff = ((nf * 16 + lr) * 128 + (kk * 32 + lg * 8) * 2) ^ swz;
          bf16x8 vb = *(const bf16x8*)((char*)VTlds + voff);
          ofrag[nf] = __builtin_amdgcn_mfma_f32_16x16x32_bf16(pa[kk], vb, ofrag[nf], 0, 0, 0);
        }
    }

    // ---- epilogue: O rows q = lg*4+r, cols d = nf*16+lr ----
    float inv = 1.0f / srun;
    float invr[4];
#pragma unroll
    for (int r = 0; r < 4; r++) invr[r] = __shfl(inv, sbase + r);
    const long orow = (long)(b * T_ + q0 + w * 16);
#pragma unroll
    for (int nf = 0; nf < 4; nf++)
#pragma unroll
      for (int r = 0; r < 4; r++)
        o[(orow + lg * 4 + r) * 2048 + h * 64 + nf * 16 + lr] = f2bf(ofrag[nf][r] * invr[r]);
  }
}

// ---------------- launch ----------------
// Workspace layout (52 MB, temporally-disjoint aliases):
//   [0,   16M) xb (x bf16)   -> reused as ab (attn out) after fused GEMM
//   [16M, 28M) wqkvT [3072][2048] (Wq^T | Wk^T | Wv^T) -> woT [2048][2048] reuses [16M,24M)
//   [28M, 52M) qkvb [4096][3072]
extern "C" void kernel_launch(void* const* d_in, const int* in_sizes, int n_in,
                              void* d_out, int out_size, void* d_ws, size_t ws_size,
                              hipStream_t stream) {
  const float* x    = (const float*)d_in[0];
  const float* Wq   = (const float*)d_in[1];
  const float* Wk   = (const float*)d_in[2];
  const float* Wv   = (const float*)d_in[3];
  const float* Wout = (const float*)d_in[4];
  const float* rsin = (const float*)d_in[5];
  const float* rcos = (const float*)d_in[6];
  const int*   swa  = (const int*)d_in[7];
  float* out = (float*)d_out;

  char* ws = (char*)d_ws;
  u16* xb    = (u16*)(ws);                      // [4096][2048]
  u16* ab    = xb;                              // alias: written after xb dead
  u16* wqkvT = (u16*)(ws + 16777216);           // [3072][2048]
  u16* woT   = wqkvT;                           // alias: written after wqkvT dead
  u16* qkvb  = (u16*)(ws + 29360128);           // [4096][3072]

  cvt_bf16_kernel<<<dim3(8192), dim3(256), 0, stream>>>(x, xb, 2097152);
  transpose_w_kernel<<<dim3(64, 64), dim3(32, 8), 0, stream>>>(Wq, wqkvT, 2048, 2048);
  transpose_w_kernel<<<dim3(16, 64), dim3(32, 8), 0, stream>>>(Wk, wqkvT + (long)2048 * 2048, 2048, 512);
  transpose_w_kernel<<<dim3(16, 64), dim3(32, 8), 0, stream>>>(Wv, wqkvT + (long)2560 * 2048, 2048, 512);

  // fused QKV projection: [4096][2048] x [3072][2048]^T -> [4096][3072]
  gemm_nt<0><<<dim3(24, 32), dim3(256), 0, stream>>>(xb, wqkvT, qkvb, 4096, 3072, 2048);

  // Wout^T into first 8MB of wqkvT's space (dead after fused GEMM)
  transpose_w_kernel<<<dim3(64, 64), dim3(32, 8), 0, stream>>>(Wout, woT, 2048, 2048);

  // RoPE over Q (cols 0..2047, folds softmax scale) + K (cols 2048..2559); V untouched
  rope_kernel<<<dim3(5, 4096), dim3(128), 0, stream>>>(qkvb, rsin, rcos, QKVS, 2560);

  // attn writes ab (= xb space); paired q-tiles, KVBLK=64: grid.x = 16
  attn_fwd<<<dim3(16, 32, 2), dim3(256), 0, stream>>>(qkvb, ab, swa);

  gemm_nt<1><<<dim3(16, 32), dim3(256), 0, stream>>>(ab, woT, out, 4096, 2048, 2048);
}